// Round 3
// baseline (747.753 us; speedup 1.0000x reference)
//
#include <hip/hip_runtime.h>
#include <hip/hip_bf16.h>
#include <stdint.h>

typedef __bf16 bf16;
typedef __attribute__((ext_vector_type(8))) __bf16 bf16x8;
typedef __attribute__((ext_vector_type(4))) __bf16 bf16x4;
typedef __attribute__((ext_vector_type(4))) float f32x4;

#define DEV __device__ __forceinline__

// problem constants
static constexpr int BB = 4, SS = 2048, DM = 1024, NH = 16, DH = 64, DMLP = 4096;
static constexpr int MR = BB * SS; // 8192 rows

DEV void gload_lds16(const void* g, void* l) {
  __builtin_amdgcn_global_load_lds(
      (const __attribute__((address_space(1))) unsigned*)g,
      (__attribute__((address_space(3))) unsigned*)l, 16, 0, 0);
}

// ---------------- weight prep ----------------
__global__ void k_prep_qkv(const float* __restrict__ wq, const float* __restrict__ wk,
                           const float* __restrict__ wv, const float* __restrict__ bq,
                           const float* __restrict__ bk, const float* __restrict__ bv,
                           bf16* __restrict__ wdst, float* __restrict__ bdst) {
  int i = blockIdx.x * 256 + threadIdx.x;            // 0 .. 3*1048576-1
  int which = i >> 20, r = i & 1048575;
  const float* src = (which == 0) ? wq : (which == 1) ? wk : wv;
  wdst[i] = (bf16)src[r];
  if (i < 3072)
    bdst[i] = (i < 1024) ? bq[i] : (i < 2048) ? bk[i - 1024] : bv[i - 2048];
}

__global__ void k_prep_wo(const float* __restrict__ wo, bf16* __restrict__ dst) {
  int i = blockIdx.x * 256 + threadIdx.x;            // 0 .. 1048575
  int d = i >> 10, k = i & 1023;
  int n = k >> 6, hh = k & 63;
  dst[i] = (bf16)wo[((size_t)n << 16) + (d << 6) + hh]; // W_O[n][d][hh]
}

__global__ void k_convert(const float* __restrict__ s, bf16* __restrict__ d) {
  int i = blockIdx.x * 256 + threadIdx.x;            // indexes float4
  float4 v = ((const float4*)s)[i];
  bf16x4 o; o[0]=(bf16)v.x; o[1]=(bf16)v.y; o[2]=(bf16)v.z; o[3]=(bf16)v.w;
  ((bf16x4*)d)[i] = o;
}

// ---------------- layernorm (fp32 in -> bf16 out) ----------------
__global__ __launch_bounds__(256)
void k_ln(const float* __restrict__ xin, const float* __restrict__ w,
          const float* __restrict__ bvec, bf16* __restrict__ out) {
  const int row = blockIdx.x, tid = threadIdx.x;
  const float4 v = ((const float4*)(xin + (size_t)row * 1024))[tid];
  float s = v.x + v.y + v.z + v.w;
  float ss = v.x*v.x + v.y*v.y + v.z*v.z + v.w*v.w;
  #pragma unroll
  for (int m = 1; m < 64; m <<= 1) { s += __shfl_xor(s, m); ss += __shfl_xor(ss, m); }
  __shared__ float red[8];
  if ((tid & 63) == 0) { red[tid >> 6] = s; red[4 + (tid >> 6)] = ss; }
  __syncthreads();
  const float S  = red[0] + red[1] + red[2] + red[3];
  const float SQ = red[4] + red[5] + red[6] + red[7];
  const float mu = S * (1.f / 1024.f);
  const float rs = rsqrtf(fmaxf(SQ * (1.f / 1024.f) - mu * mu, 0.f) + 1e-5f);
  const float4 wv = ((const float4*)w)[tid];
  const float4 bv = ((const float4*)bvec)[tid];
  bf16x4 o;
  o[0] = (bf16)((v.x - mu) * rs * wv.x + bv.x);
  o[1] = (bf16)((v.y - mu) * rs * wv.y + bv.y);
  o[2] = (bf16)((v.z - mu) * rs * wv.z + bv.z);
  o[3] = (bf16)((v.w - mu) * rs * wv.w + bv.w);
  ((bf16x4*)(out + (size_t)row * 1024))[tid] = o;
}

// ---------------- GEMM: C[m,n] = sum_k A[m,k]*Bw[n,k] + epilogue ----------------
enum { E_QKV = 0, E_OPROJ = 1, E_GELU = 2, E_FINAL = 3 };

template <int EPI>
__global__ __launch_bounds__(256, 2)
void k_gemm(const bf16* __restrict__ A, const bf16* __restrict__ Bw,
            const float* __restrict__ bias, const float* __restrict__ resid,
            void* __restrict__ Cout, int M, int N, int K) {
  __shared__ bf16 lA[128 * 32];
  __shared__ bf16 lB[128 * 32];
  const int nbn = N >> 7;
  const int nwg = gridDim.x;
  int wg = blockIdx.x;
  wg = (wg & 7) * (nwg >> 3) + (wg >> 3);      // XCD swizzle (nwg % 8 == 0 for all calls)
  const int bm = wg / nbn, bn = wg % nbn;
  const int tid = threadIdx.x, w = tid >> 6, l = tid & 63;
  const int wr = w >> 1, wc = w & 1;

  // staging: wave w loads rows [w*32, w*32+32) of each 128x32 tile, 2 issues each
  const int srow = w * 32 + (l >> 2);
  const int scb  = (l & 3) * 16;
  const char* gA = (const char*)(A + ((size_t)(bm * 128) + srow) * K) + scb;
  const char* gB = (const char*)(Bw + ((size_t)(bn * 128) + srow) * K) + scb;
  const size_t rstride = (size_t)K * 2 * 16;   // 16 rows, bytes
  char* lAp = (char*)lA + w * 2048;
  char* lBp = (char*)lB + w * 2048;

  f32x4 acc[4][4] = {};

  const int nk = K >> 5;
  for (int kt = 0; kt < nk; ++kt) {
    __syncthreads();
    const size_t ko = (size_t)kt * 64;
    gload_lds16(gA + ko, lAp);
    gload_lds16(gA + ko + rstride, lAp + 1024);
    gload_lds16(gB + ko, lBp);
    gload_lds16(gB + ko + rstride, lBp + 1024);
    asm volatile("s_waitcnt vmcnt(0)" ::: "memory");
    __syncthreads();

    bf16x8 af[4], bfr[4];
    #pragma unroll
    for (int mi = 0; mi < 4; ++mi)
      af[mi] = *(const bf16x8*)&lA[(wr * 64 + mi * 16 + (l & 15)) * 32 + (l >> 4) * 8];
    #pragma unroll
    for (int ni = 0; ni < 4; ++ni)
      bfr[ni] = *(const bf16x8*)&lB[(wc * 64 + ni * 16 + (l & 15)) * 32 + (l >> 4) * 8];
    #pragma unroll
    for (int mi = 0; mi < 4; ++mi)
      #pragma unroll
      for (int ni = 0; ni < 4; ++ni)
        acc[mi][ni] = __builtin_amdgcn_mfma_f32_16x16x32_bf16(af[mi], bfr[ni], acc[mi][ni], 0, 0, 0);
  }

  const int row0 = bm * 128 + wr * 64 + ((l >> 4) << 2);
  const int col0 = bn * 128 + wc * 64 + (l & 15);
  #pragma unroll
  for (int mi = 0; mi < 4; ++mi) {
    #pragma unroll
    for (int ni = 0; ni < 4; ++ni) {
      const int col = col0 + ni * 16;
      const float bv = bias[col];
      #pragma unroll
      for (int r = 0; r < 4; ++r) {
        const int row = row0 + mi * 16 + r;
        float v = acc[mi][ni][r] + bv;
        if (EPI == E_GELU) v = 0.5f * v * (1.0f + erff(v * 0.70710678f));
        if (EPI == E_OPROJ || EPI == E_FINAL) v += resid[(size_t)row * N + col];
        if (EPI == E_OPROJ || EPI == E_FINAL) ((float*)Cout)[(size_t)row * N + col] = v;  // fp32 out (d_out is float32!)
        else                                  ((bf16*)Cout)[(size_t)row * N + col] = (bf16)v;
      }
    }
  }
}

// ---------------- flash attention (non-causal) ----------------
// qkv: [8192][3072] bf16 (Q | K | V, each head-major h*64+dh). ctx: [8192][1024] bf16.
__global__ __launch_bounds__(256, 2)
void k_attn(const bf16* __restrict__ qkv, bf16* __restrict__ ctx) {
  __shared__ bf16 lQ[64 * 64], lK[64 * 64], lVt[64 * 64];
  __shared__ bf16 lP[4][16 * 64];
  const int tid = threadIdx.x, w = tid >> 6, l = tid & 63;
  const int qt = blockIdx.x, h = blockIdx.y, b = blockIdx.z;

  const bf16* Qg = qkv + (size_t)(b * SS + qt * 64) * 3072 + h * 64;
  const bf16* Kg = qkv + (size_t)(b * SS) * 3072 + 1024 + h * 64;
  const bf16* Vg = Kg + 1024;

  // stage Q (64x64), XOR-swizzled via pre-swizzled global source, linear LDS dest
  {
    const int row = w * 16 + (l >> 3), cs = l & 7;
    char* lp = (char*)lQ + w * 2048;
    gload_lds16((const char*)(Qg + (size_t)row * 3072) + ((cs ^ (row & 7)) * 16), lp);
    const int row2 = row + 8;
    gload_lds16((const char*)(Qg + (size_t)row2 * 3072) + ((cs ^ (row2 & 7)) * 16), lp + 1024);
  }

  float m_run[4], l_run[4];
  #pragma unroll
  for (int r = 0; r < 4; ++r) { m_run[r] = -1e30f; l_run[r] = 0.f; }
  f32x4 oacc[4] = {};
  bf16* lPw = &lP[w][0];

  for (int kv = 0; kv < SS / 64; ++kv) {
    __syncthreads();  // previous tile fully consumed
    { // stage K tile
      const int row = w * 16 + (l >> 3), cs = l & 7;
      char* lp = (char*)lK + w * 2048;
      const bf16* Kt = Kg + (size_t)(kv * 64) * 3072;
      gload_lds16((const char*)(Kt + (size_t)row * 3072) + ((cs ^ (row & 7)) * 16), lp);
      const int row2 = row + 8;
      gload_lds16((const char*)(Kt + (size_t)row2 * 3072) + ((cs ^ (row2 & 7)) * 16), lp + 1024);
    }
    { // stage V transposed (manual), swizzled
      const bf16* Vt = Vg + (size_t)(kv * 64) * 3072;
      #pragma unroll
      for (int i = 0; i < 2; ++i) {
        const int cidx = tid + 256 * i;            // 0..511
        const int key = cidx >> 3, dg = cidx & 7;
        bf16x8 v = *(const bf16x8*)(Vt + (size_t)key * 3072 + dg * 8);
        #pragma unroll
        for (int j = 0; j < 8; ++j) {
          const int d = dg * 8 + j;
          const int byteoff = d * 128 + (((key >> 3) ^ (d & 7)) * 16) + (key & 7) * 2;
          *(bf16*)((char*)lVt + byteoff) = v[j];
        }
      }
    }
    asm volatile("s_waitcnt vmcnt(0)" ::: "memory");
    __syncthreads();

    // S = Q K^T  (per wave: 16 q rows x 64 keys)
    f32x4 s[4] = {};
    bf16x8 aq[2];
    {
      const int qrow = w * 16 + (l & 15);
      #pragma unroll
      for (int c = 0; c < 2; ++c) {
        const int slot = (c * 4 + (l >> 4)) ^ (qrow & 7);
        aq[c] = *(const bf16x8*)((const char*)lQ + qrow * 128 + slot * 16);
      }
    }
    #pragma unroll
    for (int kt4 = 0; kt4 < 4; ++kt4) {
      const int krow = kt4 * 16 + (l & 15);
      #pragma unroll
      for (int c = 0; c < 2; ++c) {
        const int slot = (c * 4 + (l >> 4)) ^ (krow & 7);
        bf16x8 bk = *(const bf16x8*)((const char*)lK + krow * 128 + slot * 16);
        s[kt4] = __builtin_amdgcn_mfma_f32_16x16x32_bf16(aq[c], bk, s[kt4], 0, 0, 0);
      }
    }
    #pragma unroll
    for (int kt4 = 0; kt4 < 4; ++kt4) s[kt4] *= 0.125f;  // 1/sqrt(64)

    // online softmax; lane holds S[q=(l>>4)*4+r][key=kt4*16+(l&15)]
    float scl[4], rsum[4];
    #pragma unroll
    for (int r = 0; r < 4; ++r) {
      float mx = fmaxf(fmaxf(s[0][r], s[1][r]), fmaxf(s[2][r], s[3][r]));
      #pragma unroll
      for (int msk = 1; msk < 16; msk <<= 1) mx = fmaxf(mx, __shfl_xor(mx, msk));
      const float mn = fmaxf(m_run[r], mx);
      scl[r] = __expf(m_run[r] - mn);
      m_run[r] = mn;
      rsum[r] = 0.f;
    }
    #pragma unroll
    for (int kt4 = 0; kt4 < 4; ++kt4) {
      #pragma unroll
      for (int r = 0; r < 4; ++r) {
        const float p = __expf(s[kt4][r] - m_run[r]);
        rsum[r] += p;
        const int q = ((l >> 4) << 2) + r;
        const int key = kt4 * 16 + (l & 15);
        const int byteoff = q * 128 + (((key >> 3) ^ (q & 7)) * 16) + (key & 7) * 2;
        *(bf16*)((char*)lPw + byteoff) = (bf16)p;
      }
    }
    #pragma unroll
    for (int r = 0; r < 4; ++r) {
      float rs = rsum[r];
      #pragma unroll
      for (int msk = 1; msk < 16; msk <<= 1) rs += __shfl_xor(rs, msk);
      l_run[r] = l_run[r] * scl[r] + rs;
      #pragma unroll
      for (int dt = 0; dt < 4; ++dt) oacc[dt][r] *= scl[r];
    }

    // O += P V
    #pragma unroll
    for (int c = 0; c < 2; ++c) {
      const int prow = l & 15;
      const int pslot = (c * 4 + (l >> 4)) ^ (prow & 7);
      bf16x8 pa = *(const bf16x8*)((const char*)lPw + prow * 128 + pslot * 16);
      #pragma unroll
      for (int dt = 0; dt < 4; ++dt) {
        const int vrow = dt * 16 + (l & 15);
        const int vslot = (c * 4 + (l >> 4)) ^ (vrow & 7);
        bf16x8 vb = *(const bf16x8*)((const char*)lVt + vrow * 128 + vslot * 16);
        oacc[dt] = __builtin_amdgcn_mfma_f32_16x16x32_bf16(pa, vb, oacc[dt], 0, 0, 0);
      }
    }
  }

  const int row0 = b * SS + qt * 64 + w * 16 + ((l >> 4) << 2);
  const int col0 = h * 64 + (l & 15);
  #pragma unroll
  for (int r = 0; r < 4; ++r) {
    const float inv = 1.0f / l_run[r];
    #pragma unroll
    for (int dt = 0; dt < 4; ++dt)
      ctx[(size_t)(row0 + r) * 1024 + col0 + dt * 16] = (bf16)(oacc[dt][r] * inv);
  }
}

// ---------------- launch ----------------
extern "C" void kernel_launch(void* const* d_in, const int* in_sizes, int n_in,
                              void* d_out, int out_size, void* d_ws, size_t ws_size,
                              hipStream_t stream) {
  const float* x    = (const float*)d_in[0];
  const float* ln1w = (const float*)d_in[1];
  const float* ln1b = (const float*)d_in[2];
  const float* WQ   = (const float*)d_in[3];
  const float* bQ   = (const float*)d_in[4];
  const float* WK   = (const float*)d_in[5];
  const float* bK   = (const float*)d_in[6];
  const float* WV   = (const float*)d_in[7];
  const float* bV   = (const float*)d_in[8];
  const float* WO   = (const float*)d_in[9];
  const float* bO   = (const float*)d_in[10];
  const float* ln2w = (const float*)d_in[11];
  const float* ln2b = (const float*)d_in[12];
  const float* Win  = (const float*)d_in[13];
  const float* bin  = (const float*)d_in[14];
  const float* Wout = (const float*)d_in[15];
  const float* bout = (const float*)d_in[16];

  char* ws = (char*)d_ws;
  const size_t NEED = (size_t)3072*1024*2 + (size_t)1024*1024*2 + (size_t)4096*1024*2
                    + (size_t)1024*4096*2 + 3072*4 + (size_t)MR*1024*4
                    + (size_t)MR*1024*2 + (size_t)MR*3072*2 + (size_t)MR*1024*2;
  if (ws_size < NEED) return;  // diagnostic fail mode (output stays zero)

  bf16*  wqkv = (bf16*)ws;  ws += (size_t)3072 * 1024 * 2;
  bf16*  wo   = (bf16*)ws;  ws += (size_t)1024 * 1024 * 2;
  bf16*  win  = (bf16*)ws;  ws += (size_t)4096 * 1024 * 2;
  bf16*  wout = (bf16*)ws;  ws += (size_t)1024 * 4096 * 2;
  float* bqkv = (float*)ws; ws += 3072 * 4;
  float* xattn= (float*)ws; ws += (size_t)MR * 1024 * 4;
  bf16*  xln  = (bf16*)ws;  ws += (size_t)MR * 1024 * 2;
  bf16*  qkv  = (bf16*)ws;  ws += (size_t)MR * 3072 * 2;
  bf16*  ctx  = (bf16*)ws;  ws += (size_t)MR * 1024 * 2;
  bf16*  acts = qkv;        // reuse qkv+ctx region: 8192*4096*2 bytes exactly

  k_prep_qkv<<<3 * 1048576 / 256, 256, 0, stream>>>(WQ, WK, WV, bQ, bK, bV, wqkv, bqkv);
  k_prep_wo<<<1048576 / 256, 256, 0, stream>>>(WO, wo);
  k_convert<<<4194304 / 1024, 256, 0, stream>>>(Win, win);
  k_convert<<<4194304 / 1024, 256, 0, stream>>>(Wout, wout);

  k_ln<<<MR, 256, 0, stream>>>(x, ln1w, ln1b, xln);
  k_gemm<E_QKV><<<(MR / 128) * (3072 / 128), 256, 0, stream>>>(xln, wqkv, bqkv, nullptr, qkv, MR, 3072, 1024);
  k_attn<<<dim3(SS / 64, NH, BB), 256, 0, stream>>>(qkv, ctx);
  k_gemm<E_OPROJ><<<(MR / 128) * (1024 / 128), 256, 0, stream>>>(ctx, wo, bO, x, xattn, MR, 1024, 1024);
  k_ln<<<MR, 256, 0, stream>>>(xattn, ln2w, ln2b, xln);
  k_gemm<E_GELU><<<(MR / 128) * (4096 / 128), 256, 0, stream>>>(xln, win, bin, nullptr, acts, MR, 4096, 1024);
  k_gemm<E_FINAL><<<(MR / 128) * (1024 / 128), 256, 0, stream>>>(acts, wout, bout, xattn, (float*)d_out, MR, 1024, 4096);
}

// Round 4
// 628.667 us; speedup vs baseline: 1.1894x; 1.1894x over previous
//
#include <hip/hip_runtime.h>
#include <hip/hip_bf16.h>
#include <stdint.h>

typedef __bf16 bf16;
typedef __attribute__((ext_vector_type(8))) __bf16 bf16x8;
typedef __attribute__((ext_vector_type(4))) __bf16 bf16x4;
typedef __attribute__((ext_vector_type(4))) float f32x4;

#define DEV __device__ __forceinline__

// problem constants
static constexpr int BB = 4, SS = 2048, DM = 1024, NH = 16, DH = 64, DMLP = 4096;
static constexpr int MR = BB * SS; // 8192 rows

DEV void gload_lds16(const void* g, void* l) {
  __builtin_amdgcn_global_load_lds(
      (const __attribute__((address_space(1))) unsigned*)g,
      (__attribute__((address_space(3))) unsigned*)l, 16, 0, 0);
}

DEV uint32_t pk2(float a, float b) {
  bf16 x = (bf16)a, y = (bf16)b;
  uint16_t xa = __builtin_bit_cast(uint16_t, x), ya = __builtin_bit_cast(uint16_t, y);
  return (uint32_t)xa | ((uint32_t)ya << 16);
}

// ---------------- weight prep ----------------
__global__ void k_prep_qkv(const float* __restrict__ wq, const float* __restrict__ wk,
                           const float* __restrict__ wv, const float* __restrict__ bq,
                           const float* __restrict__ bk, const float* __restrict__ bv,
                           bf16* __restrict__ wdst, float* __restrict__ bdst) {
  int i = blockIdx.x * 256 + threadIdx.x;            // 0 .. 3*1048576-1
  int which = i >> 20, r = i & 1048575;
  const float* src = (which == 0) ? wq : (which == 1) ? wk : wv;
  wdst[i] = (bf16)src[r];
  if (i < 3072)
    bdst[i] = (i < 1024) ? bq[i] : (i < 2048) ? bk[i - 1024] : bv[i - 2048];
}

__global__ void k_prep_wo(const float* __restrict__ wo, bf16* __restrict__ dst) {
  int i = blockIdx.x * 256 + threadIdx.x;            // 0 .. 1048575
  int d = i >> 10, k = i & 1023;
  int n = k >> 6, hh = k & 63;
  dst[i] = (bf16)wo[((size_t)n << 16) + (d << 6) + hh]; // W_O[n][d][hh]
}

__global__ void k_convert(const float* __restrict__ s, bf16* __restrict__ d) {
  int i = blockIdx.x * 256 + threadIdx.x;            // indexes float4
  float4 v = ((const float4*)s)[i];
  bf16x4 o; o[0]=(bf16)v.x; o[1]=(bf16)v.y; o[2]=(bf16)v.z; o[3]=(bf16)v.w;
  ((bf16x4*)d)[i] = o;
}

// ---------------- layernorm (fp32 in -> bf16 out) ----------------
__global__ __launch_bounds__(256)
void k_ln(const float* __restrict__ xin, const float* __restrict__ w,
          const float* __restrict__ bvec, bf16* __restrict__ out) {
  const int row = blockIdx.x, tid = threadIdx.x;
  const float4 v = ((const float4*)(xin + (size_t)row * 1024))[tid];
  float s = v.x + v.y + v.z + v.w;
  float ss = v.x*v.x + v.y*v.y + v.z*v.z + v.w*v.w;
  #pragma unroll
  for (int m = 1; m < 64; m <<= 1) { s += __shfl_xor(s, m); ss += __shfl_xor(ss, m); }
  __shared__ float red[8];
  if ((tid & 63) == 0) { red[tid >> 6] = s; red[4 + (tid >> 6)] = ss; }
  __syncthreads();
  const float S  = red[0] + red[1] + red[2] + red[3];
  const float SQ = red[4] + red[5] + red[6] + red[7];
  const float mu = S * (1.f / 1024.f);
  const float rs = rsqrtf(fmaxf(SQ * (1.f / 1024.f) - mu * mu, 0.f) + 1e-5f);
  const float4 wv = ((const float4*)w)[tid];
  const float4 bv = ((const float4*)bvec)[tid];
  bf16x4 o;
  o[0] = (bf16)((v.x - mu) * rs * wv.x + bv.x);
  o[1] = (bf16)((v.y - mu) * rs * wv.y + bv.y);
  o[2] = (bf16)((v.z - mu) * rs * wv.z + bv.z);
  o[3] = (bf16)((v.w - mu) * rs * wv.w + bv.w);
  ((bf16x4*)(out + (size_t)row * 1024))[tid] = o;
}

// ---------------- GEMM: C[m,n] = sum_k A[m,k]*Bw[n,k] + epilogue ----------------
enum { E_QKV = 0, E_OPROJ = 1, E_GELU = 2, E_FINAL = 3 };

template <int EPI>
__global__ __launch_bounds__(256, 2)
void k_gemm(const bf16* __restrict__ A, const bf16* __restrict__ Bw,
            const float* __restrict__ bias, const float* __restrict__ resid,
            void* __restrict__ Cout, int M, int N, int K) {
  __shared__ bf16 lA[128 * 32];
  __shared__ bf16 lB[128 * 32];
  const int nbn = N >> 7;
  const int nwg = gridDim.x;
  int wg = blockIdx.x;
  wg = (wg & 7) * (nwg >> 3) + (wg >> 3);      // XCD swizzle (nwg % 8 == 0 for all calls)
  const int bm = wg / nbn, bn = wg % nbn;
  const int tid = threadIdx.x, w = tid >> 6, l = tid & 63;
  const int wr = w >> 1, wc = w & 1;

  // staging: wave w loads rows [w*32, w*32+32) of each 128x32 tile, 2 issues each
  const int srow = w * 32 + (l >> 2);
  const int scb  = (l & 3) * 16;
  const char* gA = (const char*)(A + ((size_t)(bm * 128) + srow) * K) + scb;
  const char* gB = (const char*)(Bw + ((size_t)(bn * 128) + srow) * K) + scb;
  const size_t rstride = (size_t)K * 2 * 16;   // 16 rows, bytes
  char* lAp = (char*)lA + w * 2048;
  char* lBp = (char*)lB + w * 2048;

  f32x4 acc[4][4] = {};

  const int nk = K >> 5;
  for (int kt = 0; kt < nk; ++kt) {
    __syncthreads();
    const size_t ko = (size_t)kt * 64;
    gload_lds16(gA + ko, lAp);
    gload_lds16(gA + ko + rstride, lAp + 1024);
    gload_lds16(gB + ko, lBp);
    gload_lds16(gB + ko + rstride, lBp + 1024);
    asm volatile("s_waitcnt vmcnt(0)" ::: "memory");
    __syncthreads();

    bf16x8 af[4], bfr[4];
    #pragma unroll
    for (int mi = 0; mi < 4; ++mi)
      af[mi] = *(const bf16x8*)&lA[(wr * 64 + mi * 16 + (l & 15)) * 32 + (l >> 4) * 8];
    #pragma unroll
    for (int ni = 0; ni < 4; ++ni)
      bfr[ni] = *(const bf16x8*)&lB[(wc * 64 + ni * 16 + (l & 15)) * 32 + (l >> 4) * 8];
    #pragma unroll
    for (int mi = 0; mi < 4; ++mi)
      #pragma unroll
      for (int ni = 0; ni < 4; ++ni)
        acc[mi][ni] = __builtin_amdgcn_mfma_f32_16x16x32_bf16(af[mi], bfr[ni], acc[mi][ni], 0, 0, 0);
  }

  const int row0 = bm * 128 + wr * 64 + ((l >> 4) << 2);
  const int col0 = bn * 128 + wc * 64 + (l & 15);
  #pragma unroll
  for (int mi = 0; mi < 4; ++mi) {
    #pragma unroll
    for (int ni = 0; ni < 4; ++ni) {
      const int col = col0 + ni * 16;
      const float bv = bias[col];
      #pragma unroll
      for (int r = 0; r < 4; ++r) {
        const int row = row0 + mi * 16 + r;
        float v = acc[mi][ni][r] + bv;
        if (EPI == E_GELU) v = 0.5f * v * (1.0f + erff(v * 0.70710678f));
        if (EPI == E_OPROJ || EPI == E_FINAL) v += resid[(size_t)row * N + col];
        if (EPI == E_OPROJ || EPI == E_FINAL) ((float*)Cout)[(size_t)row * N + col] = v;  // fp32 out
        else                                  ((bf16*)Cout)[(size_t)row * N + col] = (bf16)v;
      }
    }
  }
}

// ---------------- flash attention (non-causal), HK-style swapped layout ----------------
// qkv: [8192][3072] bf16 (Q | K | V, each head-major hd*64+dh). ctx: [8192][1024] bf16.
// Per wave: 16 q-rows (chunk w). S^T = mfma(K,Q): lane owns q = l&15, keys (l>>4)*4+r per block.
// P^T built in-register (cvt_pk + ds_bpermute). V via subtiled LDS + ds_read_b64_tr_b16.
__global__ __launch_bounds__(256)
void k_attn(const bf16* __restrict__ qkv, bf16* __restrict__ ctx) {
  __shared__ bf16 lQ[64 * 64], lK[64 * 64], lV[64 * 64];
  const int tid = threadIdx.x, w = tid >> 6, l = tid & 63;
  const int g = l >> 4, r15 = l & 15;
  const int qt = blockIdx.x, hd = blockIdx.y, b = blockIdx.z;

  const bf16* Qg = qkv + (size_t)(b * SS + qt * 64) * 3072 + hd * 64;
  const bf16* Kg = qkv + (size_t)(b * SS) * 3072 + 1024 + hd * 64;
  const bf16* Vg = Kg + 1024;

  // stage Q (64x64) row-major, XOR-swizzled via pre-swizzled global source
  {
    const int row = w * 16 + (l >> 3), cs = l & 7;
    char* lp = (char*)lQ + w * 2048;
    gload_lds16((const char*)(Qg + (size_t)row * 3072) + ((cs ^ (row & 7)) * 16), lp);
    const int row2 = row + 8;
    gload_lds16((const char*)(Qg + (size_t)row2 * 3072) + ((cs ^ (row2 & 7)) * 16), lp + 1024);
  }
  asm volatile("s_waitcnt vmcnt(0)" ::: "memory");
  __syncthreads();

  // hoist Q fragments (constant over kv tiles): B-frag = Q[w*16 + r15][c*32 + g*8 + e]
  bf16x8 bq[2];
  {
    const int qrow = w * 16 + r15;
    #pragma unroll
    for (int c = 0; c < 2; ++c) {
      const int slot = (c * 4 + g) ^ (qrow & 7);
      bq[c] = *(const bf16x8*)((const char*)lQ + qrow * 128 + slot * 16);
    }
  }

  // V staging source mapping (subtiled LDS [k/4][d/16][4][16])
  const int vk = (l >> 5) * 4 + ((l >> 1) & 3);       // + w*8 (+32 second issue)
  const int vd = ((l >> 3) & 3) * 16 + (l & 1) * 8;

  // per-lane tr-read base (AS3 byte address): group g reads tile ks=2g(+..), lane col r15
  const uint32_t vbase =
      (uint32_t)(uintptr_t)(__attribute__((address_space(3))) bf16*)lV + g * 1024 + r15 * 8;

  float m_run = -1e30f, l_run = 0.f;
  f32x4 oacc[4] = {};

  for (int kv = 0; kv < SS / 64; ++kv) {
    __syncthreads();  // previous tile fully consumed
    { // stage K tile (row-major swizzled, like Q)
      const int row = w * 16 + (l >> 3), cs = l & 7;
      char* lp = (char*)lK + w * 2048;
      const bf16* Kt = Kg + (size_t)(kv * 64) * 3072;
      gload_lds16((const char*)(Kt + (size_t)row * 3072) + ((cs ^ (row & 7)) * 16), lp);
      const int row2 = row + 8;
      gload_lds16((const char*)(Kt + (size_t)row2 * 3072) + ((cs ^ (row2 & 7)) * 16), lp + 1024);
    }
    { // stage V tile (subtiled for tr_read): wave w covers keys w*8..w*8+7 (+32)
      const bf16* Vt = Vg + (size_t)(kv * 64) * 3072;
      char* lp = (char*)lV + w * 1024;
      gload_lds16(Vt + (size_t)(w * 8 + vk) * 3072 + vd, lp);
      gload_lds16(Vt + (size_t)(w * 8 + vk + 32) * 3072 + vd, lp + 4096);
    }
    asm volatile("s_waitcnt vmcnt(0)" ::: "memory");
    __syncthreads();

    // S^T = K·Q^T : s[kt4] holds S^T[kt4*16 + g*4 + r][q = l&15] (scaled later)
    f32x4 s[4] = {};
    #pragma unroll
    for (int kt4 = 0; kt4 < 4; ++kt4) {
      const int krow = kt4 * 16 + r15;
      #pragma unroll
      for (int c = 0; c < 2; ++c) {
        const int slot = (c * 4 + g) ^ (krow & 7);
        bf16x8 kf = *(const bf16x8*)((const char*)lK + krow * 128 + slot * 16);
        s[kt4] = __builtin_amdgcn_mfma_f32_16x16x32_bf16(kf, bq[c], s[kt4], 0, 0, 0);
      }
    }
    #pragma unroll
    for (int kt4 = 0; kt4 < 4; ++kt4) s[kt4] *= 0.125f;   // 1/sqrt(64)

    // online softmax for row q = l&15 (this lane holds 16 of the row's 64 scores)
    float pmax = -1e30f;
    #pragma unroll
    for (int kt4 = 0; kt4 < 4; ++kt4)
      #pragma unroll
      for (int r = 0; r < 4; ++r) pmax = fmaxf(pmax, s[kt4][r]);
    pmax = fmaxf(pmax, __shfl_xor(pmax, 16));
    pmax = fmaxf(pmax, __shfl_xor(pmax, 32));
    const float mn = fmaxf(m_run, pmax);
    const float scl = __expf(m_run - mn);
    m_run = mn;
    float rsum = 0.f;
    #pragma unroll
    for (int kt4 = 0; kt4 < 4; ++kt4)
      #pragma unroll
      for (int r = 0; r < 4; ++r) {
        const float p = __expf(s[kt4][r] - m_run);
        s[kt4][r] = p;
        rsum += p;
      }
    rsum += __shfl_xor(rsum, 16);
    rsum += __shfl_xor(rsum, 32);
    l_run = l_run * scl + rsum;
    #pragma unroll
    for (int dt = 0; dt < 4; ++dt) oacc[dt] *= scl;

    // pack P to bf16 pairs: Dw[kt][w2] = (P[q][kt*16+g*4+2w2], P[..+1])
    uint32_t Dw[4][2];
    #pragma unroll
    for (int kt4 = 0; kt4 < 4; ++kt4) {
      Dw[kt4][0] = pk2(s[kt4][0], s[kt4][1]);
      Dw[kt4][1] = pk2(s[kt4][2], s[kt4][3]);
    }

    // build B-frags P^T for the two kk-halves: lane l elem e = P[q=l&15][kk=hh*32+g*8+e]
    union PF { bf16x8 v; uint32_t u[4]; } pf[2];
    const int s0 = (((g & 1) * 2) * 16 + r15) * 4;   // bpermute byte index
    const int s1 = s0 + 64;
    const bool hiKt = (g >> 1);                       // lanes 32..63 need kt = h*2+1
    #pragma unroll
    for (int hh = 0; hh < 2; ++hh) {
      #pragma unroll
      for (int w2 = 0; w2 < 2; ++w2) {
        const int a0 = __builtin_amdgcn_ds_bpermute(s0, (int)Dw[hh * 2][w2]);
        const int a1 = __builtin_amdgcn_ds_bpermute(s0, (int)Dw[hh * 2 + 1][w2]);
        const int b0 = __builtin_amdgcn_ds_bpermute(s1, (int)Dw[hh * 2][w2]);
        const int b1 = __builtin_amdgcn_ds_bpermute(s1, (int)Dw[hh * 2 + 1][w2]);
        pf[hh].u[w2]     = (uint32_t)(hiKt ? a1 : a0);
        pf[hh].u[2 + w2] = (uint32_t)(hiKt ? b1 : b0);
      }
    }

    // V^T fragments via hardware transpose read; tile (ks=hh*8+2g+sub, ds=dt) at (ks*4+ds)*128B
    bf16x4 tr[4][2][2];
    #pragma unroll
    for (int dt = 0; dt < 4; ++dt)
      #pragma unroll
      for (int hh = 0; hh < 2; ++hh)
        #pragma unroll
        for (int sub = 0; sub < 2; ++sub) {
          const uint32_t a = vbase + hh * 4096 + sub * 512 + dt * 128;
          asm volatile("ds_read_b64_tr_b16 %0, %1" : "=v"(tr[dt][hh][sub]) : "v"(a));
        }
    asm volatile("s_waitcnt lgkmcnt(0)" ::: "memory");
    __builtin_amdgcn_sched_barrier(0);

    // O^T += V^T · P^T  (A rows = d' = l&15 within dt block, cols q)
    #pragma unroll
    for (int dt = 0; dt < 4; ++dt) {
      #pragma unroll
      for (int hh = 0; hh < 2; ++hh) {
        bf16x8 av;
        #pragma unroll
        for (int j = 0; j < 4; ++j) { av[j] = tr[dt][hh][0][j]; av[4 + j] = tr[dt][hh][1][j]; }
        oacc[dt] = __builtin_amdgcn_mfma_f32_16x16x32_bf16(av, pf[hh].v, oacc[dt], 0, 0, 0);
      }
    }
  }

  // epilogue: O^T[d][q] -> ctx[q][d]; lane writes 4 contiguous d per dt block
  const float inv = 1.0f / l_run;
  const size_t row_out = (size_t)(b * SS + qt * 64 + w * 16 + r15);
  #pragma unroll
  for (int dt = 0; dt < 4; ++dt) {
    bf16x4 o4;
    #pragma unroll
    for (int r = 0; r < 4; ++r) o4[r] = (bf16)(oacc[dt][r] * inv);
    *(bf16x4*)(ctx + row_out * 1024 + hd * 64 + dt * 16 + g * 4) = o4;
  }
}

// ---------------- launch ----------------
extern "C" void kernel_launch(void* const* d_in, const int* in_sizes, int n_in,
                              void* d_out, int out_size, void* d_ws, size_t ws_size,
                              hipStream_t stream) {
  const float* x    = (const float*)d_in[0];
  const float* ln1w = (const float*)d_in[1];
  const float* ln1b = (const float*)d_in[2];
  const float* WQ   = (const float*)d_in[3];
  const float* bQ   = (const float*)d_in[4];
  const float* WK   = (const float*)d_in[5];
  const float* bK   = (const float*)d_in[6];
  const float* WV   = (const float*)d_in[7];
  const float* bV   = (const float*)d_in[8];
  const float* WO   = (const float*)d_in[9];
  const float* bO   = (const float*)d_in[10];
  const float* ln2w = (const float*)d_in[11];
  const float* ln2b = (const float*)d_in[12];
  const float* Win  = (const float*)d_in[13];
  const float* bin  = (const float*)d_in[14];
  const float* Wout = (const float*)d_in[15];
  const float* bout = (const float*)d_in[16];

  char* ws = (char*)d_ws;
  const size_t NEED = (size_t)3072*1024*2 + (size_t)1024*1024*2 + (size_t)4096*1024*2
                    + (size_t)1024*4096*2 + 3072*4 + (size_t)MR*1024*4
                    + (size_t)MR*1024*2 + (size_t)MR*3072*2 + (size_t)MR*1024*2;
  if (ws_size < NEED) return;  // diagnostic fail mode (output stays zero)

  bf16*  wqkv = (bf16*)ws;  ws += (size_t)3072 * 1024 * 2;
  bf16*  wo   = (bf16*)ws;  ws += (size_t)1024 * 1024 * 2;
  bf16*  win  = (bf16*)ws;  ws += (size_t)4096 * 1024 * 2;
  bf16*  wout = (bf16*)ws;  ws += (size_t)1024 * 4096 * 2;
  float* bqkv = (float*)ws; ws += 3072 * 4;
  float* xattn= (float*)ws; ws += (size_t)MR * 1024 * 4;
  bf16*  xln  = (bf16*)ws;  ws += (size_t)MR * 1024 * 2;
  bf16*  qkv  = (bf16*)ws;  ws += (size_t)MR * 3072 * 2;
  bf16*  ctx  = (bf16*)ws;  ws += (size_t)MR * 1024 * 2;
  bf16*  acts = qkv;        // reuse qkv+ctx region: 8192*4096*2 bytes exactly

  k_prep_qkv<<<3 * 1048576 / 256, 256, 0, stream>>>(WQ, WK, WV, bQ, bK, bV, wqkv, bqkv);
  k_prep_wo<<<1048576 / 256, 256, 0, stream>>>(WO, wo);
  k_convert<<<4194304 / 1024, 256, 0, stream>>>(Win, win);
  k_convert<<<4194304 / 1024, 256, 0, stream>>>(Wout, wout);

  k_ln<<<MR, 256, 0, stream>>>(x, ln1w, ln1b, xln);
  k_gemm<E_QKV><<<(MR / 128) * (3072 / 128), 256, 0, stream>>>(xln, wqkv, bqkv, nullptr, qkv, MR, 3072, 1024);
  k_attn<<<dim3(SS / 64, NH, BB), 256, 0, stream>>>(qkv, ctx);
  k_gemm<E_OPROJ><<<(MR / 128) * (1024 / 128), 256, 0, stream>>>(ctx, wo, bO, x, xattn, MR, 1024, 1024);
  k_ln<<<MR, 256, 0, stream>>>(xattn, ln2w, ln2b, xln);
  k_gemm<E_GELU><<<(MR / 128) * (4096 / 128), 256, 0, stream>>>(xln, win, bin, nullptr, acts, MR, 4096, 1024);
  k_gemm<E_FINAL><<<(MR / 128) * (1024 / 128), 256, 0, stream>>>(acts, wout, bout, xattn, (float*)d_out, MR, 1024, 4096);
}